// Round 5
// baseline (3377.128 us; speedup 1.0000x reference)
//
#include <hip/hip_runtime.h>
#include <math.h>

// Problem constants
#define BATCH 32
#define SEQ 256
#define EMBD 256
#define HDIM 256          // per-direction hidden
#define G4H 1024          // 4*H gates per direction
#define TAGS 12
#define START_IDX 10
#define STOP_IDX 11
#define NEGV -10000.0f

// ---------------- Workspace layout (floats) ----------------
#define WS_XG    0              // xg   [2][8192][1024]
#define WS_X     16777216       // x [8192][256]; after gemm reused for hx exchange
#define WS_WPACK 18874368       // wpack [2][8][1024][32] (k-comb transposed whh)
#define WS_HALL  19398656       // h_all[32][256][512]
#define WS_FEATS 23592960       // feats[32][256][12]
// hx: [2 dir][2 parity][256 units][32 batch] uint64 = 1 MB, aliases x region.
#define WS_HX    WS_X

// ---------------- Kernel 1: gather embeddings ----------------
__global__ void gather_x(const int* __restrict__ sent, const float* __restrict__ emb,
                         float* __restrict__ x) {
    int m = blockIdx.x;            // 8192 positions (b*256+s)
    int lane = threadIdx.x;        // 64
    long long row = sent[m];
    float4 v = *(const float4*)(emb + row * EMBD + lane * 4);
    *(float4*)(x + (size_t)m * EMBD + lane * 4) = v;
}

// ---------------- Kernel 2: pack whh for v5 ----------------
// pack[((dir*8+ks)*1024 + g)*32 + m] = whh_dir[g][ks + 8*m]
// (thread in lstm owns k-comb ks: k = ks+8m, loads float4 over m)
__global__ void pack_whh(const float* __restrict__ whh_f, const float* __restrict__ whh_b,
                         float* __restrict__ pack) {
    int idx = blockIdx.x * 256 + threadIdx.x;      // 2*8*1024*32 = 524288
    if (idx >= 524288) return;
    int m = idx & 31;
    int g = (idx >> 5) & 1023;
    int ks = (idx >> 15) & 7;
    int dir = idx >> 18;
    const float* w = dir ? whh_b : whh_f;
    pack[idx] = w[(size_t)g * HDIM + ks + 8 * m];
}

// ---------------- Kernel 3: xg GEMM  C[8192][2048] ----------------
__launch_bounds__(256)
__global__ void gemm_xg(const float* __restrict__ x,
                        const float* __restrict__ wih_f, const float* __restrict__ wih_b,
                        const float* __restrict__ bih_f, const float* __restrict__ bhh_f,
                        const float* __restrict__ bih_b, const float* __restrict__ bhh_b,
                        float* __restrict__ xg) {
    __shared__ __align__(16) float as[8][128];
    __shared__ __align__(16) float bs[8][128];
    int m0 = blockIdx.x * 128;     // 64 tiles
    int n0 = blockIdx.y * 128;     // 16 tiles
    int tid = threadIdx.x;
    int tx = tid & 15, ty = tid >> 4;
    int lr = tid >> 1;             // 0..127 tile row
    int lh = (tid & 1) * 4;        // k offset 0 or 4

    const float* arow = x + (size_t)(m0 + lr) * EMBD;
    const float* brow;
    {
        int n = n0 + lr;
        const float* w = (n < G4H) ? wih_f : wih_b;
        brow = w + (size_t)(n & 1023) * EMBD;
    }

    float acc[8][8];
    #pragma unroll
    for (int i = 0; i < 8; i++)
        #pragma unroll
        for (int j = 0; j < 8; j++) acc[i][j] = 0.f;

    for (int k0 = 0; k0 < EMBD; k0 += 8) {
        float4 av = *(const float4*)(arow + k0 + lh);
        float4 bv = *(const float4*)(brow + k0 + lh);
        __syncthreads();
        as[lh + 0][lr] = av.x; as[lh + 1][lr] = av.y; as[lh + 2][lr] = av.z; as[lh + 3][lr] = av.w;
        bs[lh + 0][lr] = bv.x; bs[lh + 1][lr] = bv.y; bs[lh + 2][lr] = bv.z; bs[lh + 3][lr] = bv.w;
        __syncthreads();
        #pragma unroll
        for (int kk = 0; kk < 8; kk++) {
            float4 a0 = *(const float4*)&as[kk][ty * 8];
            float4 a1 = *(const float4*)&as[kk][ty * 8 + 4];
            float4 b0 = *(const float4*)&bs[kk][tx * 8];
            float4 b1 = *(const float4*)&bs[kk][tx * 8 + 4];
            float a[8] = {a0.x, a0.y, a0.z, a0.w, a1.x, a1.y, a1.z, a1.w};
            float b[8] = {b0.x, b0.y, b0.z, b0.w, b1.x, b1.y, b1.z, b1.w};
            #pragma unroll
            for (int i = 0; i < 8; i++)
                #pragma unroll
                for (int j = 0; j < 8; j++) acc[i][j] += a[i] * b[j];
        }
    }

    int n = n0 + tx * 8;
    int dir = n >> 10, g0 = n & 1023;
    const float* bih = dir ? bih_b : bih_f;
    const float* bhh = dir ? bhh_b : bhh_f;
    float bi[8], bh[8];
    #pragma unroll
    for (int j = 0; j < 8; j++) { bi[j] = bih[g0 + j]; bh[j] = bhh[g0 + j]; }
    float* ob = xg + (size_t)dir * 8192 * G4H;
    #pragma unroll
    for (int i = 0; i < 8; i++) {
        int m = m0 + ty * 8 + i;
        float v[8];
        #pragma unroll
        for (int j = 0; j < 8; j++) v[j] = (acc[i][j] + bi[j]) + bh[j];
        *(float4*)(ob + (size_t)m * G4H + g0)     = make_float4(v[0], v[1], v[2], v[3]);
        *(float4*)(ob + (size_t)m * G4H + g0 + 4) = make_float4(v[4], v[5], v[6], v[7]);
    }
}

// ---------------- Kernel 4: LSTM recurrence (v5, batched GEMM form) -------
// 64 WGs = 2 dir x 32 slices; WG owns 8 hidden units (32 gate-rows) for ALL
// 32 batches. Weights register-resident (asm-anchored). h for the whole
// direction in LDS (k-major, 36-pad: conflict-free b128). Per-step cross-WG
// h exchange via RELAXED agent-scope u64 atomics packing (tag, f32) —
// no fences, no cache invalidation, parity double-buffered, poison-safe.
// Thread layout: tid = bg(3b) | rg(4b) | ks(3b): batch-group of 4, row-pair,
// K-comb k = ks+8m. shfl_xor(1,2,4) reduces the 8-way K split in-wave.
__launch_bounds__(1024, 4)
__global__ void lstm_rec(const float* __restrict__ xg,
                         const float* __restrict__ wpk,
                         float* __restrict__ h_all,
                         unsigned long long* __restrict__ hx) {
    int blk = blockIdx.x;          // 64
    int dir = blk & 1, slice = blk >> 1;     // slice 0..31
    int tid = threadIdx.x;
    int ks = tid & 7;
    int rg = (tid >> 3) & 15;
    int bg = tid >> 7;             // 0..7 (wave-uniform)
    int r0 = rg * 2, r1 = r0 + 1;  // local gate-rows 0..31 (r = q*8+u)
    int g0 = (r0 >> 3) * 256 + slice * 8 + (r0 & 7);
    int g1 = (r1 >> 3) * 256 + slice * 8 + (r1 & 7);

    __shared__ __align__(16) float h_lds[256 * 36];   // 36 KB, k-major +36 pad
    __shared__ float gates_lds[32 * 33];              // 4.2 KB

    // register-resident weights: 2 rows x (k = ks+8m, m in [0,32)) = 16 float4
    float4 wa[8], wb[8];
    {
        const float* base = wpk + ((size_t)(dir * 8 + ks) * 1024) * 32;
        #pragma unroll
        for (int n = 0; n < 8; n++) {
            wa[n] = *(const float4*)(base + (size_t)g0 * 32 + n * 4);
            wb[n] = *(const float4*)(base + (size_t)g1 * 32 + n * 4);
        }
    }
    // anchor: opaque asm forces values to live in VGPRs (no re-load sinking)
    #pragma unroll
    for (int n = 0; n < 8; n++) {
        asm volatile("" : "+v"(wa[n].x), "+v"(wa[n].y), "+v"(wa[n].z), "+v"(wa[n].w));
        asm volatile("" : "+v"(wb[n].x), "+v"(wb[n].y), "+v"(wb[n].z), "+v"(wb[n].w));
    }

    for (int i = tid; i < 256 * 36; i += 1024) h_lds[i] = 0.f;

    // activation-thread identity (tid < 256): unit au, batch ab
    int au = tid >> 5, ab = tid & 31;
    int aglob = slice * 8 + au;
    float c = 0.f;

    unsigned long long* hxd = hx + (size_t)dir * 2 * 256 * 32;

    __syncthreads();

    for (int t = 0; t < SEQ; t++) {
        int s = dir ? (SEQ - 1 - t) : t;

        // xg for this step (issued early; consumed after the barrier)
        float xgv[4];
        if (tid < 256) {
            const float* xb = xg + (size_t)dir * 8192 * G4H + ((size_t)ab * SEQ + s) * G4H;
            #pragma unroll
            for (int q = 0; q < 4; q++) xgv[q] = xb[q * 256 + aglob];
        }

        // ---- phase A: FMA (weights in regs, h from LDS) ----
        float4 acc0 = make_float4(0.f, 0.f, 0.f, 0.f);
        float4 acc1 = make_float4(0.f, 0.f, 0.f, 0.f);
        const float* hbase = h_lds + bg * 4;
        #pragma unroll
        for (int n = 0; n < 8; n++) {
            #pragma unroll
            for (int j = 0; j < 4; j++) {
                int k = ks + 8 * (n * 4 + j);
                float4 hb = *(const float4*)(hbase + k * 36);
                float w0 = (&wa[n].x)[j];
                float w1 = (&wb[n].x)[j];
                acc0.x += w0 * hb.x; acc0.y += w0 * hb.y;
                acc0.z += w0 * hb.z; acc0.w += w0 * hb.w;
                acc1.x += w1 * hb.x; acc1.y += w1 * hb.y;
                acc1.z += w1 * hb.z; acc1.w += w1 * hb.w;
            }
        }
        // in-wave reduction over ks (lanes xor 1,2,4) — fixed order
        #pragma unroll
        for (int off = 1; off <= 4; off <<= 1) {
            acc0.x += __shfl_xor(acc0.x, off); acc0.y += __shfl_xor(acc0.y, off);
            acc0.z += __shfl_xor(acc0.z, off); acc0.w += __shfl_xor(acc0.w, off);
            acc1.x += __shfl_xor(acc1.x, off); acc1.y += __shfl_xor(acc1.y, off);
            acc1.z += __shfl_xor(acc1.z, off); acc1.w += __shfl_xor(acc1.w, off);
        }
        if (ks == 0) {
            int c0 = bg * 4;
            gates_lds[r0 * 33 + c0 + 0] = acc0.x; gates_lds[r0 * 33 + c0 + 1] = acc0.y;
            gates_lds[r0 * 33 + c0 + 2] = acc0.z; gates_lds[r0 * 33 + c0 + 3] = acc0.w;
            gates_lds[r1 * 33 + c0 + 0] = acc1.x; gates_lds[r1 * 33 + c0 + 1] = acc1.y;
            gates_lds[r1 * 33 + c0 + 2] = acc1.z; gates_lds[r1 * 33 + c0 + 3] = acc1.w;
        }
        __syncthreads();

        // ---- phase C: activation (tid<256 = waves 0..3, no divergence) ----
        float hval = 0.f;
        if (tid < 256) {
            float gi  = gates_lds[(0 * 8 + au) * 33 + ab] + xgv[0];
            float gf  = gates_lds[(1 * 8 + au) * 33 + ab] + xgv[1];
            float gg2 = gates_lds[(2 * 8 + au) * 33 + ab] + xgv[2];
            float go  = gates_lds[(3 * 8 + au) * 33 + ab] + xgv[3];
            float si = 1.f / (1.f + expf(-gi));
            float sf = 1.f / (1.f + expf(-gf));
            float so = 1.f / (1.f + expf(-go));
            c = sf * c + si * tanhf(gg2);
            hval = so * tanhf(c);
            h_all[((size_t)ab * SEQ + s) * 512 + dir * HDIM + aglob] = hval;
        }

        if (t + 1 < SEQ) {
            int par = (t + 1) & 1;
            unsigned long long* slot = hxd + (size_t)par * 256 * 32;
            if (tid < 256) {
                unsigned long long pk =
                    ((unsigned long long)(unsigned)(t + 1) << 32) |
                    (unsigned long long)__float_as_uint(hval);
                __hip_atomic_store(&slot[aglob * 32 + ab], pk,
                                   __ATOMIC_RELAXED, __HIP_MEMORY_SCOPE_AGENT);
            }
            // ---- phase D: gather all 256 units x 32 batches (8 slots/thread)
            unsigned int want = (unsigned)(t + 1);
            int base = tid * 8;
            float hv[8];
            unsigned int got = 0;
            while (got != 0xFFu) {
                #pragma unroll
                for (int i = 0; i < 8; i++) {
                    if (!(got & (1u << i))) {
                        unsigned long long v = __hip_atomic_load(&slot[base + i],
                            __ATOMIC_RELAXED, __HIP_MEMORY_SCOPE_AGENT);
                        if ((unsigned)(v >> 32) == want) {
                            hv[i] = __uint_as_float((unsigned)v);
                            got |= 1u << i;
                        }
                    }
                }
                if (got != 0xFFu) __builtin_amdgcn_s_sleep(1);
            }
            #pragma unroll
            for (int i = 0; i < 8; i++) {
                int f = base + i;
                h_lds[(f >> 5) * 36 + (f & 31)] = hv[i];
            }
            __syncthreads();
        }
    }
}

// ---------------- Kernel 5: output projection (feats) ----------------
__global__ void feats_kernel(const float* __restrict__ h_all, const float* __restrict__ w_out,
                             const float* __restrict__ b_out, float* __restrict__ feats) {
    int p = blockIdx.x;            // 8192
    int lane = threadIdx.x;        // 64
    const float* h = h_all + (size_t)p * 512;
    for (int f = 0; f < TAGS; f++) {
        float s = 0.f;
        const float* w = w_out + f * 512;
        #pragma unroll
        for (int k = 0; k < 512; k += 64) s += h[k + lane] * w[k + lane];
        #pragma unroll
        for (int off = 32; off; off >>= 1) s += __shfl_down(s, off);
        if (lane == 0) feats[(size_t)p * TAGS + f] = s + b_out[f];
    }
}

// ---------------- Kernel 6: Viterbi decode ----------------
__global__ void viterbi_kernel(const float* __restrict__ feats, const float* __restrict__ trans,
                               float* __restrict__ out) {
    int b = blockIdx.x;            // 32
    int t = threadIdx.x;           // 64
    __shared__ float fv[TAGS], fvn[TAGS], tr[TAGS * TAGS];
    __shared__ int bp[SEQ][TAGS];  // 12 KB

    for (int i = t; i < TAGS * TAGS; i += 64) tr[i] = trans[i];
    if (t < TAGS) fv[t] = (t == START_IDX) ? 0.f : NEGV;
    __syncthreads();

    const float* fb = feats + (size_t)b * SEQ * TAGS;
    for (int s = 0; s < SEQ; s++) {
        if (t < TAGS) {
            float best = fv[0] + tr[t * TAGS + 0];
            int bi = 0;
            #pragma unroll
            for (int prev = 1; prev < TAGS; prev++) {
                float v = fv[prev] + tr[t * TAGS + prev];
                if (v > best) { best = v; bi = prev; }   // first-index argmax
            }
            bp[s][t] = bi;
            fvn[t] = best + fb[s * TAGS + t];
        }
        __syncthreads();
        if (t < TAGS) fv[t] = fvn[t];
        __syncthreads();
    }

    if (t == 0) {
        float best = fv[0] + tr[STOP_IDX * TAGS + 0];
        int bi = 0;
        #pragma unroll
        for (int p = 1; p < TAGS; p++) {
            float v = fv[p] + tr[STOP_IDX * TAGS + p];
            if (v > best) { best = v; bi = p; }
        }
        out[b] = best;                                   // score
        float* path = out + BATCH + (size_t)b * SEQ;
        int tag = bi;
        path[SEQ - 1] = (float)tag;
        for (int s = SEQ - 1; s >= 1; s--) {
            tag = bp[s][tag];
            path[s - 1] = (float)tag;
        }
    }
}

// ---------------- Launch ----------------
extern "C" void kernel_launch(void* const* d_in, const int* in_sizes, int n_in,
                              void* d_out, int out_size, void* d_ws, size_t ws_size,
                              hipStream_t stream) {
    const int*   sent  = (const int*)d_in[0];
    const float* emb   = (const float*)d_in[1];
    const float* wih_f = (const float*)d_in[2];
    const float* whh_f = (const float*)d_in[3];
    const float* bih_f = (const float*)d_in[4];
    const float* bhh_f = (const float*)d_in[5];
    const float* wih_b = (const float*)d_in[6];
    const float* whh_b = (const float*)d_in[7];
    const float* bih_b = (const float*)d_in[8];
    const float* bhh_b = (const float*)d_in[9];
    const float* w_out = (const float*)d_in[10];
    const float* b_out = (const float*)d_in[11];
    const float* trans = (const float*)d_in[12];
    float* ws    = (float*)d_ws;
    float* xg    = ws + WS_XG;
    float* x     = ws + WS_X;
    float* wpack = ws + WS_WPACK;
    float* h_all = ws + WS_HALL;
    float* feats = ws + WS_FEATS;
    unsigned long long* hx = (unsigned long long*)(ws + WS_HX);  // aliases x (dead after gemm)
    float* out   = (float*)d_out;

    gather_x<<<BATCH * SEQ, 64, 0, stream>>>(sent, emb, x);
    pack_whh<<<2048, 256, 0, stream>>>(whh_f, whh_b, wpack);
    gemm_xg<<<dim3(64, 16), 256, 0, stream>>>(x, wih_f, wih_b, bih_f, bhh_f, bih_b, bhh_b, xg);
    // hx tags: harness poison 0xAAAA... never equals a valid tag (1..256) — no memset needed
    lstm_rec<<<64, 1024, 0, stream>>>(xg, wpack, h_all, hx);
    feats_kernel<<<BATCH * SEQ, 64, 0, stream>>>(h_all, w_out, b_out, feats);
    viterbi_kernel<<<BATCH, 64, 0, stream>>>(feats, trans, out);
}

// Round 6
// 1950.830 us; speedup vs baseline: 1.7311x; 1.7311x over previous
//
#include <hip/hip_runtime.h>
#include <math.h>

// Problem constants
#define BATCH 32
#define SEQ 256
#define EMBD 256
#define HDIM 256          // per-direction hidden
#define G4H 1024          // 4*H gates per direction
#define TAGS 12
#define START_IDX 10
#define STOP_IDX 11
#define NEGV -10000.0f

// Recurrence weight residency (float4 K-groups of 16 KB each, 64 total):
//   LDS   : groups [0,9)   -> 144 KB dynamic LDS (160 KB/CU cap)
//   AGPR  : groups [9,25)  -> 64 floats/thread via explicit v_accvgpr asm
//                             (64 VGPR + 64 AGPR = 128 = cap @ 4 waves/SIMD)
//   stream: groups [25,64) -> 39 groups = 624 KB/WG/step from L2
//                             ~10.0k lines/step @ ~1 line/cyc/CU
#define KLG 9
#define KAG 16
#define KSG 39
#define DYN_FLOATS (KLG * 4096 + 512 + 1024)   // wlds + hbuf[2][256] + gates[1024]

// ---------------- Workspace layout (floats) ----------------
#define WS_XG    0              // xg   [2][8192][1024]
#define WS_X     16777216       // x    [8192][256]
#define WS_WPACK 18874368       // wpack[2][64][1024] float4
#define WS_HALL  19398656       // h_all[32][256][512]
#define WS_FEATS 23592960       // feats[32][256][12]

// ---------------- Kernel 1: gather embeddings ----------------
__global__ void gather_x(const int* __restrict__ sent, const float* __restrict__ emb,
                         float* __restrict__ x) {
    int m = blockIdx.x;            // 8192 positions (b*256+s)
    int lane = threadIdx.x;        // 64
    long long row = sent[m];
    float4 v = *(const float4*)(emb + row * EMBD + lane * 4);
    *(float4*)(x + (size_t)m * EMBD + lane * 4) = v;
}

// ---------------- Kernel 2: transpose whh into [dir][k4][g] float4 pack ----
__global__ void pack_whh(const float* __restrict__ whh_f, const float* __restrict__ whh_b,
                         float4* __restrict__ pack) {
    int idx = blockIdx.x * 256 + threadIdx.x;      // 2*64*1024 = 131072
    if (idx >= 2 * 64 * G4H) return;
    int g = idx & 1023;
    int k4 = (idx >> 10) & 63;
    int dir = idx >> 16;
    const float* w = dir ? whh_b : whh_f;
    pack[idx] = *(const float4*)(w + (size_t)g * HDIM + k4 * 4);
}

// ---------------- Kernel 3: xg GEMM  C[8192][2048] ----------------
__launch_bounds__(256)
__global__ void gemm_xg(const float* __restrict__ x,
                        const float* __restrict__ wih_f, const float* __restrict__ wih_b,
                        const float* __restrict__ bih_f, const float* __restrict__ bhh_f,
                        const float* __restrict__ bih_b, const float* __restrict__ bhh_b,
                        float* __restrict__ xg) {
    __shared__ __align__(16) float as[8][128];
    __shared__ __align__(16) float bs[8][128];
    int m0 = blockIdx.x * 128;     // 64 tiles
    int n0 = blockIdx.y * 128;     // 16 tiles
    int tid = threadIdx.x;
    int tx = tid & 15, ty = tid >> 4;
    int lr = tid >> 1;             // 0..127 tile row
    int lh = (tid & 1) * 4;        // k offset 0 or 4

    const float* arow = x + (size_t)(m0 + lr) * EMBD;
    const float* brow;
    {
        int n = n0 + lr;
        const float* w = (n < G4H) ? wih_f : wih_b;
        brow = w + (size_t)(n & 1023) * EMBD;
    }

    float acc[8][8];
    #pragma unroll
    for (int i = 0; i < 8; i++)
        #pragma unroll
        for (int j = 0; j < 8; j++) acc[i][j] = 0.f;

    for (int k0 = 0; k0 < EMBD; k0 += 8) {
        float4 av = *(const float4*)(arow + k0 + lh);
        float4 bv = *(const float4*)(brow + k0 + lh);
        __syncthreads();
        as[lh + 0][lr] = av.x; as[lh + 1][lr] = av.y; as[lh + 2][lr] = av.z; as[lh + 3][lr] = av.w;
        bs[lh + 0][lr] = bv.x; bs[lh + 1][lr] = bv.y; bs[lh + 2][lr] = bv.z; bs[lh + 3][lr] = bv.w;
        __syncthreads();
        #pragma unroll
        for (int kk = 0; kk < 8; kk++) {
            float4 a0 = *(const float4*)&as[kk][ty * 8];
            float4 a1 = *(const float4*)&as[kk][ty * 8 + 4];
            float4 b0 = *(const float4*)&bs[kk][tx * 8];
            float4 b1 = *(const float4*)&bs[kk][tx * 8 + 4];
            float a[8] = {a0.x, a0.y, a0.z, a0.w, a1.x, a1.y, a1.z, a1.w};
            float b[8] = {b0.x, b0.y, b0.z, b0.w, b1.x, b1.y, b1.z, b1.w};
            #pragma unroll
            for (int i = 0; i < 8; i++)
                #pragma unroll
                for (int j = 0; j < 8; j++) acc[i][j] += a[i] * b[j];
        }
    }

    int n = n0 + tx * 8;
    int dir = n >> 10, g0 = n & 1023;
    const float* bih = dir ? bih_b : bih_f;
    const float* bhh = dir ? bhh_b : bhh_f;
    float bi[8], bh[8];
    #pragma unroll
    for (int j = 0; j < 8; j++) { bi[j] = bih[g0 + j]; bh[j] = bhh[g0 + j]; }
    float* ob = xg + (size_t)dir * 8192 * G4H;
    #pragma unroll
    for (int i = 0; i < 8; i++) {
        int m = m0 + ty * 8 + i;
        float v[8];
        #pragma unroll
        for (int j = 0; j < 8; j++) v[j] = (acc[i][j] + bi[j]) + bh[j];
        *(float4*)(ob + (size_t)m * G4H + g0)     = make_float4(v[0], v[1], v[2], v[3]);
        *(float4*)(ob + (size_t)m * G4H + g0 + 4) = make_float4(v[4], v[5], v[6], v[7]);
    }
}

// ---------------- Kernel 4: LSTM recurrence (v6: LDS + AGPR residency) ----
// 64 WGs x 1024 threads, thread g owns gate row g. K order is ascending
// (LDS [0,9), AGPR [9,25), stream [25,64)) with the same per-group
// expression as the R3 kernel -> bit-identical accumulation.
__launch_bounds__(1024)
__global__ void lstm_rec(const float* __restrict__ xg,
                         const float4* __restrict__ wpack,
                         float* __restrict__ h_all) {
    extern __shared__ __align__(16) float dyn[];
    float4* wlds = (float4*)dyn;                 // KLG*1024 float4 = 144 KB
    float*  hbuf = dyn + KLG * 4096;             // [2][256]
    float*  gates = hbuf + 512;                  // [1024]

    int blk = blockIdx.x;          // 64
    int dir = blk & 1, b = blk >> 1;
    int g = threadIdx.x;           // gate 0..1023
    const float4* wp = wpack + (size_t)dir * 64 * G4H;
    const float* xgb = xg + (size_t)dir * 8192 * G4H + (size_t)b * SEQ * G4H;

    // LDS-resident weights: K-groups [0,9)
    for (int i = g; i < KLG * G4H; i += 1024) wlds[i] = wp[i];

    // AGPR-resident weights: K-groups [9,25) -> 64 floats in explicit AGPRs.
    // "a"-class values cannot be re-materialized from memory by the compiler.
    float ag[KAG * 4];
    #pragma unroll
    for (int i = 0; i < KAG; i++) {
        float4 w = wp[(KLG + i) * G4H + g];
        asm volatile("v_accvgpr_write_b32 %0, %1" : "=a"(ag[4 * i + 0]) : "v"(w.x));
        asm volatile("v_accvgpr_write_b32 %0, %1" : "=a"(ag[4 * i + 1]) : "v"(w.y));
        asm volatile("v_accvgpr_write_b32 %0, %1" : "=a"(ag[4 * i + 2]) : "v"(w.z));
        asm volatile("v_accvgpr_write_b32 %0, %1" : "=a"(ag[4 * i + 3]) : "v"(w.w));
    }

    const float4* gw = wp + (KLG + KAG) * G4H;   // streamed K-groups [25,64)

    float c = 0.f;
    if (g < HDIM) hbuf[g] = 0.f;                 // hbuf[0][g]
    __syncthreads();

    int s0 = dir ? (SEQ - 1) : 0;
    float xnext = xgb[(size_t)s0 * G4H + g];

    for (int t = 0; t < SEQ; t++) {
        int s = dir ? (SEQ - 1 - t) : t;
        const float* hc = hbuf + (t & 1) * HDIM;
        float acc = xnext;

        if (t + 1 < SEQ) {                       // prefetch next xg (h-independent)
            int sn = dir ? (SEQ - 2 - t) : (t + 1);
            xnext = xgb[(size_t)sn * G4H + g];
        }

        // LDS segment: k 0..35
        #pragma unroll
        for (int k4 = 0; k4 < KLG; k4++) {
            float4 h4 = *(const float4*)&hc[k4 * 4];
            float4 w4 = wlds[k4 * G4H + g];
            acc += w4.x * h4.x + w4.y * h4.y + w4.z * h4.z + w4.w * h4.w;
        }
        // AGPR segment: k 36..99
        #pragma unroll
        for (int i = 0; i < KAG; i++) {
            float4 h4 = *(const float4*)&hc[(KLG + i) * 4];
            float wx, wy, wz, wv;
            asm volatile("v_accvgpr_read_b32 %0, %1" : "=v"(wx) : "a"(ag[4 * i + 0]));
            asm volatile("v_accvgpr_read_b32 %0, %1" : "=v"(wy) : "a"(ag[4 * i + 1]));
            asm volatile("v_accvgpr_read_b32 %0, %1" : "=v"(wz) : "a"(ag[4 * i + 2]));
            asm volatile("v_accvgpr_read_b32 %0, %1" : "=v"(wv) : "a"(ag[4 * i + 3]));
            acc += wx * h4.x + wy * h4.y + wz * h4.z + wv * h4.w;
        }
        // L2-streamed segment: k 100..255
        #pragma unroll 5
        for (int k4 = 0; k4 < KSG; k4++) {
            float4 h4 = *(const float4*)&hc[(KLG + KAG + k4) * 4];
            float4 w4 = gw[(size_t)k4 * G4H + g];
            acc += w4.x * h4.x + w4.y * h4.y + w4.z * h4.z + w4.w * h4.w;
        }

        gates[g] = acc;
        __syncthreads();
        if (g < HDIM) {
            float gi = gates[g], gf = gates[HDIM + g];
            float gg2 = gates[2 * HDIM + g], go = gates[3 * HDIM + g];
            float si = 1.f / (1.f + expf(-gi));
            float sf = 1.f / (1.f + expf(-gf));
            float so = 1.f / (1.f + expf(-go));
            c = sf * c + si * tanhf(gg2);
            float h = so * tanhf(c);
            hbuf[((t + 1) & 1) * HDIM + g] = h;
            h_all[((size_t)b * SEQ + s) * 512 + dir * HDIM + g] = h;
        }
        __syncthreads();
    }
}

// ---------------- Kernel 5: output projection (feats) ----------------
__global__ void feats_kernel(const float* __restrict__ h_all, const float* __restrict__ w_out,
                             const float* __restrict__ b_out, float* __restrict__ feats) {
    int p = blockIdx.x;            // 8192
    int lane = threadIdx.x;        // 64
    const float* h = h_all + (size_t)p * 512;
    for (int f = 0; f < TAGS; f++) {
        float s = 0.f;
        const float* w = w_out + f * 512;
        #pragma unroll
        for (int k = 0; k < 512; k += 64) s += h[k + lane] * w[k + lane];
        #pragma unroll
        for (int off = 32; off; off >>= 1) s += __shfl_down(s, off);
        if (lane == 0) feats[(size_t)p * TAGS + f] = s + b_out[f];
    }
}

// ---------------- Kernel 6: Viterbi decode ----------------
__global__ void viterbi_kernel(const float* __restrict__ feats, const float* __restrict__ trans,
                               float* __restrict__ out) {
    int b = blockIdx.x;            // 32
    int t = threadIdx.x;           // 64
    __shared__ float fv[TAGS], fvn[TAGS], tr[TAGS * TAGS];
    __shared__ int bp[SEQ][TAGS];  // 12 KB

    for (int i = t; i < TAGS * TAGS; i += 64) tr[i] = trans[i];
    if (t < TAGS) fv[t] = (t == START_IDX) ? 0.f : NEGV;
    __syncthreads();

    const float* fb = feats + (size_t)b * SEQ * TAGS;
    for (int s = 0; s < SEQ; s++) {
        if (t < TAGS) {
            float best = fv[0] + tr[t * TAGS + 0];
            int bi = 0;
            #pragma unroll
            for (int prev = 1; prev < TAGS; prev++) {
                float v = fv[prev] + tr[t * TAGS + prev];
                if (v > best) { best = v; bi = prev; }   // first-index argmax
            }
            bp[s][t] = bi;
            fvn[t] = best + fb[s * TAGS + t];
        }
        __syncthreads();
        if (t < TAGS) fv[t] = fvn[t];
        __syncthreads();
    }

    if (t == 0) {
        float best = fv[0] + tr[STOP_IDX * TAGS + 0];
        int bi = 0;
        #pragma unroll
        for (int p = 1; p < TAGS; p++) {
            float v = fv[p] + tr[STOP_IDX * TAGS + p];
            if (v > best) { best = v; bi = p; }
        }
        out[b] = best;                                   // score
        float* path = out + BATCH + (size_t)b * SEQ;
        int tag = bi;
        path[SEQ - 1] = (float)tag;
        for (int s = SEQ - 1; s >= 1; s--) {
            tag = bp[s][tag];
            path[s - 1] = (float)tag;
        }
    }
}

// ---------------- Launch ----------------
extern "C" void kernel_launch(void* const* d_in, const int* in_sizes, int n_in,
                              void* d_out, int out_size, void* d_ws, size_t ws_size,
                              hipStream_t stream) {
    const int*   sent  = (const int*)d_in[0];
    const float* emb   = (const float*)d_in[1];
    const float* wih_f = (const float*)d_in[2];
    const float* whh_f = (const float*)d_in[3];
    const float* bih_f = (const float*)d_in[4];
    const float* bhh_f = (const float*)d_in[5];
    const float* wih_b = (const float*)d_in[6];
    const float* whh_b = (const float*)d_in[7];
    const float* bih_b = (const float*)d_in[8];
    const float* bhh_b = (const float*)d_in[9];
    const float* w_out = (const float*)d_in[10];
    const float* b_out = (const float*)d_in[11];
    const float* trans = (const float*)d_in[12];
    float* ws    = (float*)d_ws;
    float* xg    = ws + WS_XG;
    float* x     = ws + WS_X;
    float* wpack = ws + WS_WPACK;
    float* h_all = ws + WS_HALL;
    float* feats = ws + WS_FEATS;
    float* out   = (float*)d_out;

    // opt in to >64 KB dynamic LDS (idempotent; not a stream op)
    (void)hipFuncSetAttribute((const void*)lstm_rec,
                              hipFuncAttributeMaxDynamicSharedMemorySize,
                              DYN_FLOATS * (int)sizeof(float));

    gather_x<<<BATCH * SEQ, 64, 0, stream>>>(sent, emb, x);
    pack_whh<<<(2 * 64 * G4H + 255) / 256, 256, 0, stream>>>(whh_f, whh_b, (float4*)wpack);
    gemm_xg<<<dim3(64, 16), 256, 0, stream>>>(x, wih_f, wih_b, bih_f, bhh_f, bih_b, bhh_b, xg);
    lstm_rec<<<64, 1024, DYN_FLOATS * sizeof(float), stream>>>(xg, (const float4*)wpack, h_all);
    feats_kernel<<<BATCH * SEQ, 64, 0, stream>>>(h_all, w_out, b_out, feats);
    viterbi_kernel<<<BATCH, 64, 0, stream>>>(feats, trans, out);
}